// Round 2
// baseline (1232.517 us; speedup 1.0000x reference)
//
#include <hip/hip_runtime.h>

#define T_TOK 2048
#define DIM 2048
#define NE 16
#define NI 1408
#define TOPK 6

typedef __bf16 bf16x8 __attribute__((ext_vector_type(8)));
typedef float f32x4 __attribute__((ext_vector_type(4)));

static __device__ __forceinline__ unsigned short f2bf(float f) {
  unsigned int u = __builtin_bit_cast(unsigned int, f);
  u += 0x7fffu + ((u >> 16) & 1u);   // round-to-nearest-even
  return (unsigned short)(u >> 16);
}

static __device__ __forceinline__ void async_load16(const void* g, void* l) {
  __builtin_amdgcn_global_load_lds(
      (const __attribute__((address_space(1))) unsigned int*)g,
      (__attribute__((address_space(3))) unsigned int*)l, 16, 0, 0);
}

// ---------------- weight fp32 -> bf16 conversion (pure BW) ----------------
__global__ __launch_bounds__(256) void cvt_w_kernel(const float* __restrict__ w,
                                                    unsigned short* __restrict__ wb) {
  size_t i = ((size_t)blockIdx.x * 256 + threadIdx.x) * 8;
  float4 v0 = *(const float4*)(w + i);
  float4 v1 = *(const float4*)(w + i + 4);
  ushort4 o0 = make_ushort4(f2bf(v0.x), f2bf(v0.y), f2bf(v0.z), f2bf(v0.w));
  ushort4 o1 = make_ushort4(f2bf(v1.x), f2bf(v1.y), f2bf(v1.z), f2bf(v1.w));
  *(ushort4*)(wb + i) = o0;
  *(ushort4*)(wb + i + 4) = o1;
}

// ---------------- router: logits -> softmax -> top6 -> combine ----------------
__global__ void router_kernel(const float* __restrict__ x, const float* __restrict__ gw,
                              float* __restrict__ combine) {
  int t = blockIdx.x;
  int l = threadIdx.x;
  const float* xr = x + (size_t)t * DIM;
  float acc[NE];
#pragma unroll
  for (int e = 0; e < NE; e++) acc[e] = 0.f;
  for (int d = l; d < DIM; d += 64) {
    float xv = xr[d];
#pragma unroll
    for (int e = 0; e < NE; e++) acc[e] += xv * gw[e * DIM + d];
  }
#pragma unroll
  for (int e = 0; e < NE; e++) {
    float v = acc[e];
#pragma unroll
    for (int s = 32; s > 0; s >>= 1) v += __shfl_down(v, s, 64);
    acc[e] = v;
  }
  if (l == 0) {
    float mx = acc[0];
#pragma unroll
    for (int e = 1; e < NE; e++) mx = fmaxf(mx, acc[e]);
    float p[NE]; float sum = 0.f;
#pragma unroll
    for (int e = 0; e < NE; e++) { p[e] = expf(acc[e] - mx); sum += p[e]; }
    float inv = 1.f / sum;
#pragma unroll
    for (int e = 0; e < NE; e++) p[e] *= inv;
    float w[NE];
#pragma unroll
    for (int e = 0; e < NE; e++) w[e] = 0.f;
    int used = 0;
    float ssum = 0.f;
    for (int k = 0; k < TOPK; k++) {
      int best = 0; float bv = -1e30f;
      for (int e = 0; e < NE; e++) {
        if (!((used >> e) & 1) && acc[e] > bv) { bv = acc[e]; best = e; }
      }
      used |= (1 << best);
      w[best] = p[best];
      ssum += p[best];
    }
    float isum = 1.f / ssum;
    for (int e = 0; e < NE; e++) combine[t * NE + e] = w[e] * isum;
  }
}

// ---------------- cast hidden_states to bf16 ----------------
__global__ void cast_x_kernel(const float* __restrict__ x, unsigned short* __restrict__ xb) {
  int i = (blockIdx.x * 256 + threadIdx.x) * 4;
  float4 v = *(const float4*)(x + i);
  ushort4 o = make_ushort4(f2bf(v.x), f2bf(v.y), f2bf(v.z), f2bf(v.w));
  *(ushort4*)(xb + i) = o;
}

// ---------------- per-expert token list building ----------------
__global__ void count_kernel(const float* __restrict__ combine, int* __restrict__ counts) {
  int e = blockIdx.x, l = threadIdx.x;
  int c = 0;
  for (int t0 = 0; t0 < T_TOK; t0 += 64) {
    bool pred = combine[(size_t)(t0 + l) * NE + e] > 0.f;
    unsigned long long m = __ballot(pred);
    c += (int)__popcll(m);
  }
  if (l == 0) counts[e] = c;
}

__global__ void scan_kernel(const int* __restrict__ counts, int* __restrict__ offsets) {
  if (threadIdx.x == 0) {
    int s = 0;
    for (int e = 0; e < NE; e++) { offsets[e] = s; s += counts[e]; }
    offsets[NE] = s;
  }
}

__global__ void fill_kernel(const float* __restrict__ combine, const int* __restrict__ offsets,
                            int* __restrict__ ids, float* __restrict__ scales) {
  int e = blockIdx.x, l = threadIdx.x;
  int base = offsets[e];
  for (int t0 = 0; t0 < T_TOK; t0 += 64) {
    int t = t0 + l;
    float w = combine[(size_t)t * NE + e];
    bool pred = w > 0.f;
    unsigned long long m = __ballot(pred);
    int idx = base + (int)__popcll(m & ((1ull << l) - 1ull));
    if (pred) { ids[idx] = t; scales[idx] = w; }
    base += (int)__popcll(m);
  }
}

// ---------------- GEMM1: h = silu(Xe @ W1g^T) * (Xe @ W1u^T), bf16 out --------
// block tile: 128 tokens x 64 i-channels, BK=64. 4 waves, each 64x32 of g and u.
// WBF16: weights pre-converted to bf16 -> B staged via global_load_lds (like A).
template<bool WBF16>
__global__ __launch_bounds__(256) void gemm1_kernel(
    const unsigned short* __restrict__ xb, const float* __restrict__ w13f,
    const unsigned short* __restrict__ w13b,
    const int* __restrict__ ids, const int* __restrict__ offsets,
    unsigned short* __restrict__ h) {
  int e = blockIdx.z;
  int off = offsets[e];
  int ne = offsets[e + 1] - off;
  int m0 = blockIdx.y * 128;
  if (m0 >= ne) return;
  int i0 = blockIdx.x * 64;

  __shared__ unsigned short At[8 * 128 * 8];   // 16 KB  [chunk][row128][8]
  __shared__ unsigned short Bg[8 * 64 * 8];    // 8 KB   [chunk][row64][8]
  __shared__ unsigned short Bu[8 * 64 * 8];    // 8 KB
  __shared__ int ids_l[128];

  int tid = threadIdx.x;
  int wave = tid >> 6, lane = tid & 63;

  if (tid < 128) {
    int s = m0 + tid;
    ids_l[tid] = (s < ne) ? ids[off + s] : 0;   // clamp partial tiles
  }
  __syncthreads();
  int gid0 = ids_l[lane];
  int gid1 = ids_l[64 + lane];
  const unsigned short* a0 = xb + (size_t)gid0 * DIM;
  const unsigned short* a1 = xb + (size_t)gid1 * DIM;

  const float* Wg = nullptr; const float* Wu = nullptr;
  const unsigned short* WgB = nullptr; const unsigned short* WuB = nullptr;
  if constexpr (WBF16) {
    WgB = w13b + (size_t)e * (2 * NI) * DIM + (size_t)(i0 + lane) * DIM;
    WuB = WgB + (size_t)NI * DIM;
  } else {
    Wg = w13f + (size_t)e * (2 * NI) * DIM + (size_t)i0 * DIM;
    Wu = Wg + (size_t)NI * DIM;
  }

  int wm = wave >> 1, wn = wave & 1;
  int quad = lane >> 4, l15 = lane & 15;

  f32x4 zf = {0.f, 0.f, 0.f, 0.f};
  f32x4 accg[4][2], accu[4][2];
#pragma unroll
  for (int a = 0; a < 4; a++)
#pragma unroll
    for (int b = 0; b < 2; b++) { accg[a][b] = zf; accu[a][b] = zf; }

  int brow = tid >> 4;          // 0..15
  int c4 = tid & 15;            // fp32 col group (4 floats)
  int bchunk = c4 >> 1;
  int hof = (c4 & 1) * 4;

  for (int k0 = 0; k0 < DIM; k0 += 64) {
    // A tile: async global->LDS, 16B/lane, chunked layout
#pragma unroll
    for (int j = 0; j < 4; j++) {
      int linear = wave * 4 + j;
      int chunk = linear >> 1;
      int half = j & 1;  // wave*4 is even
      const unsigned short* src = (half ? a1 : a0) + k0 + chunk * 8;
      async_load16(src, &At[chunk * 1024 + half * 512]);
    }
    if constexpr (WBF16) {
      // B tiles: async global->LDS, per-lane row = i0+lane
#pragma unroll
      for (int j = 0; j < 2; j++) {
        int chunk = wave * 2 + j;
        async_load16(WgB + k0 + chunk * 8, &Bg[chunk * 512]);
        async_load16(WuB + k0 + chunk * 8, &Bu[chunk * 512]);
      }
    } else {
#pragma unroll
      for (int r = 0; r < 4; r++) {
        int row = brow + r * 16;
        float4 vg = *(const float4*)(Wg + (size_t)row * DIM + k0 + c4 * 4);
        float4 vu = *(const float4*)(Wu + (size_t)row * DIM + k0 + c4 * 4);
        ushort4 og = make_ushort4(f2bf(vg.x), f2bf(vg.y), f2bf(vg.z), f2bf(vg.w));
        ushort4 ou = make_ushort4(f2bf(vu.x), f2bf(vu.y), f2bf(vu.z), f2bf(vu.w));
        *(ushort4*)&Bg[bchunk * 512 + row * 8 + hof] = og;
        *(ushort4*)&Bu[bchunk * 512 + row * 8 + hof] = ou;
      }
    }
    __syncthreads();
#pragma unroll
    for (int ks = 0; ks < 2; ks++) {
      int cb = ks * 4 + quad;
      bf16x8 af[4], bgf[2], buf_[2];
#pragma unroll
      for (int mt = 0; mt < 4; mt++)
        af[mt] = *(const bf16x8*)&At[cb * 1024 + (wm * 64 + mt * 16 + l15) * 8];
#pragma unroll
      for (int nt = 0; nt < 2; nt++) {
        bgf[nt] = *(const bf16x8*)&Bg[cb * 512 + (wn * 32 + nt * 16 + l15) * 8];
        buf_[nt] = *(const bf16x8*)&Bu[cb * 512 + (wn * 32 + nt * 16 + l15) * 8];
      }
#pragma unroll
      for (int mt = 0; mt < 4; mt++)
#pragma unroll
        for (int nt = 0; nt < 2; nt++) {
          accg[mt][nt] = __builtin_amdgcn_mfma_f32_16x16x32_bf16(af[mt], bgf[nt], accg[mt][nt], 0, 0, 0);
          accu[mt][nt] = __builtin_amdgcn_mfma_f32_16x16x32_bf16(af[mt], buf_[nt], accu[mt][nt], 0, 0, 0);
        }
    }
    __syncthreads();
  }
  // epilogue: h = silu(g) * u, store bf16
#pragma unroll
  for (int mt = 0; mt < 4; mt++)
#pragma unroll
    for (int nt = 0; nt < 2; nt++)
#pragma unroll
      for (int r = 0; r < 4; r++) {
        int row_l = wm * 64 + mt * 16 + quad * 4 + r;
        if (m0 + row_l < ne) {
          float gv = accg[mt][nt][r];
          float uv = accu[mt][nt][r];
          float hv = gv * uv / (1.f + __expf(-gv));
          int col = i0 + wn * 32 + nt * 16 + l15;
          h[(size_t)(off + m0 + row_l) * NI + col] = f2bf(hv);
        }
      }
}

// ---------------- GEMM2: out[t] += scale * (h_e @ W2^T) ----------------
// block tile: 128 token-slots x 128 d-channels, BK=64, K=1408.
template<bool WBF16>
__global__ __launch_bounds__(256) void gemm2_kernel(
    const unsigned short* __restrict__ h, const float* __restrict__ w2f,
    const unsigned short* __restrict__ w2b,
    const int* __restrict__ ids, const float* __restrict__ scales,
    const int* __restrict__ offsets, float* __restrict__ out) {
  int e = blockIdx.z;
  int off = offsets[e];
  int ne = offsets[e + 1] - off;
  int m0 = blockIdx.y * 128;
  if (m0 >= ne) return;
  int n0 = blockIdx.x * 128;

  __shared__ unsigned short At[8 * 128 * 8];   // 16 KB
  __shared__ unsigned short Bt[8 * 128 * 8];   // 16 KB
  __shared__ int ids_l[128];
  __shared__ float scl_l[128];

  int tid = threadIdx.x;
  int wave = tid >> 6, lane = tid & 63;
  if (tid < 128) {
    int s = m0 + tid;
    bool v = s < ne;
    ids_l[tid] = v ? ids[off + s] : 0;
    scl_l[tid] = v ? scales[off + s] : 0.f;
  }
  __syncthreads();

  const unsigned short* h0 = h + (size_t)(off + m0 + lane) * NI;        // h padded by 128 rows
  const unsigned short* h1 = h + (size_t)(off + m0 + 64 + lane) * NI;

  const float* W = nullptr;
  const unsigned short* WB0 = nullptr; const unsigned short* WB1 = nullptr;
  if constexpr (WBF16) {
    WB0 = w2b + (size_t)e * DIM * NI + (size_t)(n0 + lane) * NI;
    WB1 = WB0 + (size_t)64 * NI;
  } else {
    W = w2f + (size_t)e * DIM * NI;
  }

  int wm = wave >> 1, wn = wave & 1;
  int quad = lane >> 4, l15 = lane & 15;

  f32x4 zf = {0.f, 0.f, 0.f, 0.f};
  f32x4 acc[4][4];
#pragma unroll
  for (int a = 0; a < 4; a++)
#pragma unroll
    for (int b = 0; b < 4; b++) acc[a][b] = zf;

  int brow = tid >> 4, c4 = tid & 15, bchunk = c4 >> 1, hof = (c4 & 1) * 4;

  for (int k0 = 0; k0 < NI; k0 += 64) {
#pragma unroll
    for (int j = 0; j < 4; j++) {
      int linear = wave * 4 + j;
      int chunk = linear >> 1;
      int half = j & 1;
      const unsigned short* src = (half ? h1 : h0) + k0 + chunk * 8;
      async_load16(src, &At[chunk * 1024 + half * 512]);
    }
    if constexpr (WBF16) {
#pragma unroll
      for (int j = 0; j < 4; j++) {
        int linear = wave * 4 + j;
        int chunk = linear >> 1;
        int half = j & 1;
        async_load16((half ? WB1 : WB0) + k0 + chunk * 8, &Bt[chunk * 1024 + half * 512]);
      }
    } else {
#pragma unroll
      for (int r = 0; r < 8; r++) {
        int row = brow + r * 16;
        float4 v = *(const float4*)(W + (size_t)(n0 + row) * NI + k0 + c4 * 4);
        ushort4 o = make_ushort4(f2bf(v.x), f2bf(v.y), f2bf(v.z), f2bf(v.w));
        *(ushort4*)&Bt[bchunk * 1024 + row * 8 + hof] = o;
      }
    }
    __syncthreads();
#pragma unroll
    for (int ks = 0; ks < 2; ks++) {
      int cb = ks * 4 + quad;
      bf16x8 af[4], bf[4];
#pragma unroll
      for (int mt = 0; mt < 4; mt++)
        af[mt] = *(const bf16x8*)&At[cb * 1024 + (wm * 64 + mt * 16 + l15) * 8];
#pragma unroll
      for (int nt = 0; nt < 4; nt++)
        bf[nt] = *(const bf16x8*)&Bt[cb * 1024 + (wn * 64 + nt * 16 + l15) * 8];
#pragma unroll
      for (int mt = 0; mt < 4; mt++)
#pragma unroll
        for (int nt = 0; nt < 4; nt++)
          acc[mt][nt] = __builtin_amdgcn_mfma_f32_16x16x32_bf16(af[mt], bf[nt], acc[mt][nt], 0, 0, 0);
    }
    __syncthreads();
  }
#pragma unroll
  for (int mt = 0; mt < 4; mt++)
#pragma unroll
    for (int nt = 0; nt < 4; nt++)
#pragma unroll
      for (int r = 0; r < 4; r++) {
        int row_l = wm * 64 + mt * 16 + quad * 4 + r;
        if (m0 + row_l < ne) {
          int t = ids_l[row_l];
          float s = scl_l[row_l];
          int col = n0 + wn * 64 + nt * 16 + l15;
          atomicAdd(&out[(size_t)t * DIM + col], s * acc[mt][nt][r]);
        }
      }
}

extern "C" void kernel_launch(void* const* d_in, const int* in_sizes, int n_in,
                              void* d_out, int out_size, void* d_ws, size_t ws_size,
                              hipStream_t stream) {
  const float* x   = (const float*)d_in[0];
  const float* gw  = (const float*)d_in[1];
  const float* w13 = (const float*)d_in[2];
  const float* w2  = (const float*)d_in[3];
  float* out = (float*)d_out;

  char* ws = (char*)d_ws;
  // ws layout (bytes):
  //   combine  @ 0x000000  2048*16*4 = 131072
  //   counts   @ 0x020000
  //   offsets  @ 0x020100
  //   ids      @ 0x020200  12288*4
  //   scales   @ 0x02D000  12288*4
  //   x_bf16   @ 0x040000  2048*2048*2 = 8 MB
  //   h        @ 0x840000  (12288+128)*1408*2 = 34.96 MB
  //   w13_bf16 @ W13OFF    16*2816*2048*2 = 184.5 MB   (if ws allows)
  //   w2_bf16  @ W2OFF     16*2048*1408*2 = 92.3 MB    (if ws allows)
  float* combine        = (float*)(ws + 0x000000);
  int* counts           = (int*)  (ws + 0x020000);
  int* offsets          = (int*)  (ws + 0x020100);
  int* ids              = (int*)  (ws + 0x020200);
  float* scales         = (float*)(ws + 0x02D000);
  unsigned short* xb    = (unsigned short*)(ws + 0x040000);
  unsigned short* h     = (unsigned short*)(ws + 0x840000);

  const size_t n13 = (size_t)NE * 2 * NI * DIM;          // 92,274,688
  const size_t n2  = (size_t)NE * DIM * NI;              // 46,137,344
  size_t hend = 0x840000 + (size_t)(12288 + 128) * NI * 2;
  size_t w13off = (hend + 255) & ~(size_t)255;
  size_t w2off  = w13off + n13 * 2;
  size_t need13   = w2off;
  size_t needfull = w2off + n2 * 2;
  bool b13 = ws_size >= need13;
  bool b2  = ws_size >= needfull;
  unsigned short* w13b = (unsigned short*)(ws + w13off);
  unsigned short* w2b  = (unsigned short*)(ws + w2off);

  hipMemsetAsync(d_out, 0, (size_t)T_TOK * DIM * sizeof(float), stream);

  if (b13) cvt_w_kernel<<<(int)(n13 / (256 * 8)), 256, 0, stream>>>(w13, w13b);
  if (b2)  cvt_w_kernel<<<(int)(n2  / (256 * 8)), 256, 0, stream>>>(w2, w2b);

  router_kernel<<<T_TOK, 64, 0, stream>>>(x, gw, combine);
  cast_x_kernel<<<(T_TOK * DIM) / (256 * 4), 256, 0, stream>>>(x, xb);
  count_kernel<<<NE, 64, 0, stream>>>(combine, counts);
  scan_kernel<<<1, 64, 0, stream>>>(counts, offsets);
  fill_kernel<<<NE, 64, 0, stream>>>(combine, offsets, ids, scales);

  if (b13)
    gemm1_kernel<true><<<dim3(NI / 64, T_TOK / 128, NE), 256, 0, stream>>>(xb, nullptr, w13b, ids, offsets, h);
  else
    gemm1_kernel<false><<<dim3(NI / 64, T_TOK / 128, NE), 256, 0, stream>>>(xb, w13, nullptr, ids, offsets, h);

  if (b2)
    gemm2_kernel<true><<<dim3(DIM / 128, T_TOK / 128, NE), 256, 0, stream>>>(h, nullptr, w2b, ids, scales, offsets, out);
  else
    gemm2_kernel<false><<<dim3(DIM / 128, T_TOK / 128, NE), 256, 0, stream>>>(h, w2, nullptr, ids, scales, offsets, out);
}

// Round 3
// 1230.299 us; speedup vs baseline: 1.0018x; 1.0018x over previous
//
#include <hip/hip_runtime.h>

#define T_TOK 2048
#define DIM 2048
#define NE 16
#define NI 1408
#define TOPK 6

typedef __bf16 bf16x8 __attribute__((ext_vector_type(8)));
typedef float f32x4 __attribute__((ext_vector_type(4)));
typedef unsigned short u16x8 __attribute__((ext_vector_type(8)));

static __device__ __forceinline__ unsigned short f2bf(float f) {
  unsigned int u = __builtin_bit_cast(unsigned int, f);
  u += 0x7fffu + ((u >> 16) & 1u);   // round-to-nearest-even
  return (unsigned short)(u >> 16);
}

static __device__ __forceinline__ u16x8 cvt8(float4 a, float4 b) {
  u16x8 r;
  r[0] = f2bf(a.x); r[1] = f2bf(a.y); r[2] = f2bf(a.z); r[3] = f2bf(a.w);
  r[4] = f2bf(b.x); r[5] = f2bf(b.y); r[6] = f2bf(b.z); r[7] = f2bf(b.w);
  return r;
}

// ---------------- weight fp32 -> bf16 conversion (pure BW) ----------------
__global__ __launch_bounds__(256) void cvt_w_kernel(const float* __restrict__ w,
                                                    unsigned short* __restrict__ wb) {
  size_t i = ((size_t)blockIdx.x * 256 + threadIdx.x) * 8;
  float4 v0 = *(const float4*)(w + i);
  float4 v1 = *(const float4*)(w + i + 4);
  *(u16x8*)(wb + i) = cvt8(v0, v1);
}

// ---------------- router: logits -> softmax -> top6 -> combine ----------------
__global__ void router_kernel(const float* __restrict__ x, const float* __restrict__ gw,
                              float* __restrict__ combine) {
  int t = blockIdx.x;
  int l = threadIdx.x;
  const float* xr = x + (size_t)t * DIM;
  float acc[NE];
#pragma unroll
  for (int e = 0; e < NE; e++) acc[e] = 0.f;
  for (int d = l; d < DIM; d += 64) {
    float xv = xr[d];
#pragma unroll
    for (int e = 0; e < NE; e++) acc[e] += xv * gw[e * DIM + d];
  }
#pragma unroll
  for (int e = 0; e < NE; e++) {
    float v = acc[e];
#pragma unroll
    for (int s = 32; s > 0; s >>= 1) v += __shfl_down(v, s, 64);
    acc[e] = v;
  }
  if (l == 0) {
    float mx = acc[0];
#pragma unroll
    for (int e = 1; e < NE; e++) mx = fmaxf(mx, acc[e]);
    float p[NE]; float sum = 0.f;
#pragma unroll
    for (int e = 0; e < NE; e++) { p[e] = expf(acc[e] - mx); sum += p[e]; }
    float inv = 1.f / sum;
#pragma unroll
    for (int e = 0; e < NE; e++) p[e] *= inv;
    float w[NE];
#pragma unroll
    for (int e = 0; e < NE; e++) w[e] = 0.f;
    int used = 0;
    float ssum = 0.f;
    for (int k = 0; k < TOPK; k++) {
      int best = 0; float bv = -1e30f;
      for (int e = 0; e < NE; e++) {
        if (!((used >> e) & 1) && acc[e] > bv) { bv = acc[e]; best = e; }
      }
      used |= (1 << best);
      w[best] = p[best];
      ssum += p[best];
    }
    float isum = 1.f / ssum;
    for (int e = 0; e < NE; e++) combine[t * NE + e] = w[e] * isum;
  }
}

// ---------------- cast hidden_states to bf16 ----------------
__global__ void cast_x_kernel(const float* __restrict__ x, unsigned short* __restrict__ xb) {
  int i = (blockIdx.x * 256 + threadIdx.x) * 4;
  float4 v = *(const float4*)(x + i);
  ushort4 o = make_ushort4(f2bf(v.x), f2bf(v.y), f2bf(v.z), f2bf(v.w));
  *(ushort4*)(xb + i) = o;
}

// ---------------- per-expert token list building ----------------
__global__ void count_kernel(const float* __restrict__ combine, int* __restrict__ counts) {
  int e = blockIdx.x, l = threadIdx.x;
  int c = 0;
  for (int t0 = 0; t0 < T_TOK; t0 += 64) {
    bool pred = combine[(size_t)(t0 + l) * NE + e] > 0.f;
    unsigned long long m = __ballot(pred);
    c += (int)__popcll(m);
  }
  if (l == 0) counts[e] = c;
}

__global__ void scan_kernel(const int* __restrict__ counts, int* __restrict__ offsets) {
  if (threadIdx.x == 0) {
    int s = 0;
    for (int e = 0; e < NE; e++) { offsets[e] = s; s += counts[e]; }
    offsets[NE] = s;
  }
}

__global__ void fill_kernel(const float* __restrict__ combine, const int* __restrict__ offsets,
                            int* __restrict__ ids, float* __restrict__ scales) {
  int e = blockIdx.x, l = threadIdx.x;
  int base = offsets[e];
  for (int t0 = 0; t0 < T_TOK; t0 += 64) {
    int t = t0 + l;
    float w = combine[(size_t)t * NE + e];
    bool pred = w > 0.f;
    unsigned long long m = __ballot(pred);
    int idx = base + (int)__popcll(m & ((1ull << l) - 1ull));
    if (pred) { ids[idx] = t; scales[idx] = w; }
    base += (int)__popcll(m);
  }
}

// ---------------- GEMM1: h = silu(Xe @ W1g^T) * (Xe @ W1u^T), bf16 out --------
// 128 tokens x 64 i-cols (x2 matrices). Register-prefetch software pipeline:
// loads for k+1 issued after the stage-barrier, consumed at next iter's LDS
// store -> compiler places vmcnt waits there, MFMA(k) hides global latency.
template<bool WBF16>
__global__ __launch_bounds__(256) void gemm1_kernel(
    const unsigned short* __restrict__ xb, const float* __restrict__ w13f,
    const unsigned short* __restrict__ w13b,
    const int* __restrict__ ids, const int* __restrict__ offsets,
    unsigned short* __restrict__ h) {
  int e = blockIdx.z;
  int off = offsets[e];
  int ne = offsets[e + 1] - off;
  int m0 = blockIdx.y * 128;
  if (m0 >= ne) return;
  int i0 = blockIdx.x * 64;

  __shared__ unsigned short At[8 * 128 * 8];   // [chunk][row128][8]
  __shared__ unsigned short Bg[8 * 64 * 8];    // [chunk][row64][8]
  __shared__ unsigned short Bu[8 * 64 * 8];
  __shared__ int ids_l[128];

  int tid = threadIdx.x;
  int wave = tid >> 6, lane = tid & 63;

  if (tid < 128) {
    int s = m0 + tid;
    ids_l[tid] = (s < ne) ? ids[off + s] : 0;   // clamp partial tiles
  }
  __syncthreads();

  // A prefetch: row ra (0..127), chunks ca0+2j
  int ra = tid & 127, ca0 = tid >> 7;
  const unsigned short* arow = xb + (size_t)ids_l[ra] * DIM;
  // B prefetch: row rb (0..63), chunks cb0+4j
  int rb = tid & 63, cb0 = tid >> 6;
  const unsigned short* growB = nullptr; const unsigned short* urowB = nullptr;
  const float* growF = nullptr; const float* urowF = nullptr;
  if constexpr (WBF16) {
    growB = w13b + ((size_t)e * 2 * NI + i0 + rb) * DIM;
    urowB = growB + (size_t)NI * DIM;
  } else {
    growF = w13f + ((size_t)e * 2 * NI + i0 + rb) * DIM;
    urowF = growF + (size_t)NI * DIM;
  }

  u16x8 pa[4], pbg[2], pbu[2];
  float4 fbg[2][2], fbu[2][2];

  auto loadA = [&](int k0) {
#pragma unroll
    for (int j = 0; j < 4; j++) pa[j] = *(const u16x8*)(arow + k0 + (ca0 + 2 * j) * 8);
  };
  auto loadB = [&](int k0) {
    if constexpr (WBF16) {
#pragma unroll
      for (int j = 0; j < 2; j++) {
        pbg[j] = *(const u16x8*)(growB + k0 + (cb0 + 4 * j) * 8);
        pbu[j] = *(const u16x8*)(urowB + k0 + (cb0 + 4 * j) * 8);
      }
    } else {
#pragma unroll
      for (int j = 0; j < 2; j++) {
        const float* g = growF + k0 + (cb0 + 4 * j) * 8;
        const float* u = urowF + k0 + (cb0 + 4 * j) * 8;
        fbg[j][0] = *(const float4*)g; fbg[j][1] = *(const float4*)(g + 4);
        fbu[j][0] = *(const float4*)u; fbu[j][1] = *(const float4*)(u + 4);
      }
    }
  };
  auto stage = [&]() {
#pragma unroll
    for (int j = 0; j < 4; j++) *(u16x8*)&At[(ca0 + 2 * j) * 1024 + ra * 8] = pa[j];
#pragma unroll
    for (int j = 0; j < 2; j++) {
      if constexpr (WBF16) {
        *(u16x8*)&Bg[(cb0 + 4 * j) * 512 + rb * 8] = pbg[j];
        *(u16x8*)&Bu[(cb0 + 4 * j) * 512 + rb * 8] = pbu[j];
      } else {
        *(u16x8*)&Bg[(cb0 + 4 * j) * 512 + rb * 8] = cvt8(fbg[j][0], fbg[j][1]);
        *(u16x8*)&Bu[(cb0 + 4 * j) * 512 + rb * 8] = cvt8(fbu[j][0], fbu[j][1]);
      }
    }
  };

  int wm = wave >> 1, wn = wave & 1;
  int quad = lane >> 4, l15 = lane & 15;

  f32x4 zf = {0.f, 0.f, 0.f, 0.f};
  f32x4 accg[4][2], accu[4][2];
#pragma unroll
  for (int a = 0; a < 4; a++)
#pragma unroll
    for (int b = 0; b < 2; b++) { accg[a][b] = zf; accu[a][b] = zf; }

  loadA(0); loadB(0);
  for (int k0 = 0; k0 < DIM; k0 += 64) {
    __syncthreads();            // prev iter's ds_reads done -> LDS writable
    stage();                    // vmcnt waits for prefetch regs land here
    __syncthreads();
    if (k0 + 64 < DIM) { loadA(k0 + 64); loadB(k0 + 64); }   // async, hidden by MFMA
#pragma unroll
    for (int ks = 0; ks < 2; ks++) {
      int cb = ks * 4 + quad;
      bf16x8 af[4], bgf[2], buf_[2];
#pragma unroll
      for (int mt = 0; mt < 4; mt++)
        af[mt] = *(const bf16x8*)&At[cb * 1024 + (wm * 64 + mt * 16 + l15) * 8];
#pragma unroll
      for (int nt = 0; nt < 2; nt++) {
        bgf[nt] = *(const bf16x8*)&Bg[cb * 512 + (wn * 32 + nt * 16 + l15) * 8];
        buf_[nt] = *(const bf16x8*)&Bu[cb * 512 + (wn * 32 + nt * 16 + l15) * 8];
      }
#pragma unroll
      for (int mt = 0; mt < 4; mt++)
#pragma unroll
        for (int nt = 0; nt < 2; nt++) {
          accg[mt][nt] = __builtin_amdgcn_mfma_f32_16x16x32_bf16(af[mt], bgf[nt], accg[mt][nt], 0, 0, 0);
          accu[mt][nt] = __builtin_amdgcn_mfma_f32_16x16x32_bf16(af[mt], buf_[nt], accu[mt][nt], 0, 0, 0);
        }
    }
  }
  // epilogue: h = silu(g) * u, store bf16 (no LDS use -> no barrier needed)
#pragma unroll
  for (int mt = 0; mt < 4; mt++)
#pragma unroll
    for (int nt = 0; nt < 2; nt++)
#pragma unroll
      for (int r = 0; r < 4; r++) {
        int row_l = wm * 64 + mt * 16 + quad * 4 + r;
        if (m0 + row_l < ne) {
          float gv = accg[mt][nt][r];
          float uv = accu[mt][nt][r];
          float hv = gv * uv / (1.f + __expf(-gv));
          int col = i0 + wn * 32 + nt * 16 + l15;
          h[(size_t)(off + m0 + row_l) * NI + col] = f2bf(hv);
        }
      }
}

// ---------------- GEMM2: out[t] += scale * (h_e @ W2^T) ----------------
// 128 token-slots x 128 d-cols, K=1408. Same register-prefetch pipeline.
template<bool WBF16>
__global__ __launch_bounds__(256) void gemm2_kernel(
    const unsigned short* __restrict__ h, const float* __restrict__ w2f,
    const unsigned short* __restrict__ w2b,
    const int* __restrict__ ids, const float* __restrict__ scales,
    const int* __restrict__ offsets, float* __restrict__ out) {
  int e = blockIdx.z;
  int off = offsets[e];
  int ne = offsets[e + 1] - off;
  int m0 = blockIdx.y * 128;
  if (m0 >= ne) return;
  int n0 = blockIdx.x * 128;

  __shared__ unsigned short At[8 * 128 * 8];
  __shared__ unsigned short Bt[8 * 128 * 8];
  __shared__ int ids_l[128];
  __shared__ float scl_l[128];

  int tid = threadIdx.x;
  int wave = tid >> 6, lane = tid & 63;
  if (tid < 128) {
    int s = m0 + tid;
    bool v = s < ne;
    ids_l[tid] = v ? ids[off + s] : 0;
    scl_l[tid] = v ? scales[off + s] : 0.f;
  }
  __syncthreads();

  int ra = tid & 127, ca0 = tid >> 7;
  const unsigned short* arow = h + (size_t)(off + m0 + ra) * NI;  // h has +128 row pad
  int rb = tid & 127, cb0 = tid >> 7;
  const unsigned short* browB = nullptr;
  const float* browF = nullptr;
  if constexpr (WBF16) browB = w2b + ((size_t)e * DIM + n0 + rb) * NI;
  else                 browF = w2f + ((size_t)e * DIM + n0 + rb) * NI;

  u16x8 pa[4], pb[4];
  float4 fb[4][2];

  auto loadA = [&](int k0) {
#pragma unroll
    for (int j = 0; j < 4; j++) pa[j] = *(const u16x8*)(arow + k0 + (ca0 + 2 * j) * 8);
  };
  auto loadB = [&](int k0) {
    if constexpr (WBF16) {
#pragma unroll
      for (int j = 0; j < 4; j++) pb[j] = *(const u16x8*)(browB + k0 + (cb0 + 2 * j) * 8);
    } else {
#pragma unroll
      for (int j = 0; j < 4; j++) {
        const float* g = browF + k0 + (cb0 + 2 * j) * 8;
        fb[j][0] = *(const float4*)g; fb[j][1] = *(const float4*)(g + 4);
      }
    }
  };
  auto stage = [&]() {
#pragma unroll
    for (int j = 0; j < 4; j++) *(u16x8*)&At[(ca0 + 2 * j) * 1024 + ra * 8] = pa[j];
#pragma unroll
    for (int j = 0; j < 4; j++) {
      if constexpr (WBF16) *(u16x8*)&Bt[(cb0 + 2 * j) * 1024 + rb * 8] = pb[j];
      else                 *(u16x8*)&Bt[(cb0 + 2 * j) * 1024 + rb * 8] = cvt8(fb[j][0], fb[j][1]);
    }
  };

  int wm = wave >> 1, wn = wave & 1;
  int quad = lane >> 4, l15 = lane & 15;

  f32x4 zf = {0.f, 0.f, 0.f, 0.f};
  f32x4 acc[4][4];
#pragma unroll
  for (int a = 0; a < 4; a++)
#pragma unroll
    for (int b = 0; b < 4; b++) acc[a][b] = zf;

  loadA(0); loadB(0);
  for (int k0 = 0; k0 < NI; k0 += 64) {
    __syncthreads();
    stage();
    __syncthreads();
    if (k0 + 64 < NI) { loadA(k0 + 64); loadB(k0 + 64); }
#pragma unroll
    for (int ks = 0; ks < 2; ks++) {
      int cb = ks * 4 + quad;
      bf16x8 af[4], bf[4];
#pragma unroll
      for (int mt = 0; mt < 4; mt++)
        af[mt] = *(const bf16x8*)&At[cb * 1024 + (wm * 64 + mt * 16 + l15) * 8];
#pragma unroll
      for (int nt = 0; nt < 4; nt++)
        bf[nt] = *(const bf16x8*)&Bt[cb * 1024 + (wn * 64 + nt * 16 + l15) * 8];
#pragma unroll
      for (int mt = 0; mt < 4; mt++)
#pragma unroll
        for (int nt = 0; nt < 4; nt++)
          acc[mt][nt] = __builtin_amdgcn_mfma_f32_16x16x32_bf16(af[mt], bf[nt], acc[mt][nt], 0, 0, 0);
    }
  }
  // epilogue reads ids_l/scl_l (written in prologue, never overwritten)
#pragma unroll
  for (int mt = 0; mt < 4; mt++)
#pragma unroll
    for (int nt = 0; nt < 4; nt++)
#pragma unroll
      for (int r = 0; r < 4; r++) {
        int row_l = wm * 64 + mt * 16 + quad * 4 + r;
        if (m0 + row_l < ne) {
          int t = ids_l[row_l];
          float s = scl_l[row_l];
          int col = n0 + wn * 64 + nt * 16 + l15;
          atomicAdd(&out[(size_t)t * DIM + col], s * acc[mt][nt][r]);
        }
      }
}

extern "C" void kernel_launch(void* const* d_in, const int* in_sizes, int n_in,
                              void* d_out, int out_size, void* d_ws, size_t ws_size,
                              hipStream_t stream) {
  const float* x   = (const float*)d_in[0];
  const float* gw  = (const float*)d_in[1];
  const float* w13 = (const float*)d_in[2];
  const float* w2  = (const float*)d_in[3];
  float* out = (float*)d_out;

  char* ws = (char*)d_ws;
  float* combine        = (float*)(ws + 0x000000);
  int* counts           = (int*)  (ws + 0x020000);
  int* offsets          = (int*)  (ws + 0x020100);
  int* ids              = (int*)  (ws + 0x020200);
  float* scales         = (float*)(ws + 0x02D000);
  unsigned short* xb    = (unsigned short*)(ws + 0x040000);
  unsigned short* h     = (unsigned short*)(ws + 0x840000);

  const size_t n13 = (size_t)NE * 2 * NI * DIM;
  const size_t n2  = (size_t)NE * DIM * NI;
  size_t hend = 0x840000 + (size_t)(12288 + 128) * NI * 2;
  size_t w13off = (hend + 255) & ~(size_t)255;
  size_t w2off  = w13off + n13 * 2;
  size_t need13   = w2off;
  size_t needfull = w2off + n2 * 2;
  bool b13 = ws_size >= need13;
  bool b2  = ws_size >= needfull;
  unsigned short* w13b = (unsigned short*)(ws + w13off);
  unsigned short* w2b  = (unsigned short*)(ws + w2off);

  hipMemsetAsync(d_out, 0, (size_t)T_TOK * DIM * sizeof(float), stream);

  if (b13) cvt_w_kernel<<<(int)(n13 / (256 * 8)), 256, 0, stream>>>(w13, w13b);
  if (b2)  cvt_w_kernel<<<(int)(n2  / (256 * 8)), 256, 0, stream>>>(w2, w2b);

  router_kernel<<<T_TOK, 64, 0, stream>>>(x, gw, combine);
  cast_x_kernel<<<(T_TOK * DIM) / (256 * 4), 256, 0, stream>>>(x, xb);
  count_kernel<<<NE, 64, 0, stream>>>(combine, counts);
  scan_kernel<<<1, 64, 0, stream>>>(counts, offsets);
  fill_kernel<<<NE, 64, 0, stream>>>(combine, offsets, ids, scales);

  if (b13)
    gemm1_kernel<true><<<dim3(NI / 64, T_TOK / 128, NE), 256, 0, stream>>>(xb, nullptr, w13b, ids, offsets, h);
  else
    gemm1_kernel<false><<<dim3(NI / 64, T_TOK / 128, NE), 256, 0, stream>>>(xb, w13, nullptr, ids, offsets, h);

  if (b2)
    gemm2_kernel<true><<<dim3(DIM / 128, T_TOK / 128, NE), 256, 0, stream>>>(h, nullptr, w2b, ids, scales, offsets, out);
  else
    gemm2_kernel<false><<<dim3(DIM / 128, T_TOK / 128, NE), 256, 0, stream>>>(h, w2, nullptr, ids, scales, offsets, out);
}